// Round 5
// baseline (357.499 us; speedup 1.0000x reference)
//
#include <hip/hip_runtime.h>

// out[b,c,h,w] = alpha[slot[b,h,w], c] * x[b,c,h,w] + beta[slot[b,h,w], c]
// x: [B, C, H, W] f32; alpha/beta: [S, C] f32; slot: [B, H, W] i32
// B=16, C=256, S=256, H=W=112 -> HW=12544
//
// R5 == R4 with the nontemporal-store type fixed (needs a native clang
// vector type, not HIP_vector_type<float,4>).
//  - TC=4 -> xv[4] (16 VGPRs), natural VGPR ~50 (<=64 -> 8 waves/SIMD).
//  - grid 2048 blocks (SPLITS=2 x 64 c-tiles x 16 b) -> 8 blocks/CU,
//    32 waves/CU possible; 6 iters/thread for cross-iteration overlap.
//  - LDS 8 KB/block (tab[4][256] float2) -> LDS never the occupancy cap.
//  - non-temporal f32x4 stores: don't write-allocate 200 MB of out into
//    L2/L3, keep x L3-resident (FETCH was 103 MB = half of x from L3).
//  - NO launch_bounds min-waves clamp (R2: forced spills broke timing).

#define NUM_SLOTS 256
#define CHANNELS  256
#define TC        4             // channels per block (c-tile)
#define HW        12544         // 112*112
#define HW4       3136          // HW/4 (float4 spatial positions)
#define SPLITS    2             // spatial splits per (b, c-tile)
#define CHUNK     1568          // HW4 / SPLITS

typedef float f32x4 __attribute__((ext_vector_type(4)));
typedef float f32x2 __attribute__((ext_vector_type(2)));
typedef int   i32x4 __attribute__((ext_vector_type(4)));

__global__ __launch_bounds__(256) void slot_affine_kernel(
    const float* __restrict__ x,
    const float* __restrict__ alpha,
    const float* __restrict__ beta,
    const int*   __restrict__ slot,
    float*       __restrict__ out)
{
    // interleaved {alpha, beta} for this block's 4 channels, all 256 slots: 8 KB
    __shared__ f32x2 tab[TC][NUM_SLOTS];

    const int t     = threadIdx.x;   // 0..255
    const int split = blockIdx.x;    // 0..SPLITS-1
    const int ct    = blockIdx.y;    // 0..C/TC-1
    const int b     = blockIdx.z;    // 0..B-1
    const int c0    = ct * TC;

    // ---- stage tables: thread t owns slot row s = t ----
    {
        const f32x4 a4 = *reinterpret_cast<const f32x4*>(alpha + (size_t)t * CHANNELS + c0);
        const f32x4 b4 = *reinterpret_cast<const f32x4*>(beta  + (size_t)t * CHANNELS + c0);
        // consecutive lanes -> consecutive slots -> 2-lanes/bank (free)
        tab[0][t] = (f32x2){a4.x, b4.x};
        tab[1][t] = (f32x2){a4.y, b4.y};
        tab[2][t] = (f32x2){a4.z, b4.z};
        tab[3][t] = (f32x2){a4.w, b4.w};
    }
    __syncthreads();

    const i32x4* slot4 = reinterpret_cast<const i32x4*>(slot + (size_t)b * HW);
    const f32x4* xp    = reinterpret_cast<const f32x4*>(x    + ((size_t)b * CHANNELS + c0) * HW);
    f32x4*       op    = reinterpret_cast<f32x4*>      (out  + ((size_t)b * CHANNELS + c0) * HW);

    const int pbase = split * CHUNK;
    const int pend  = pbase + CHUNK;

    for (int p = pbase + t; p < pend; p += 256) {
        const i32x4 s4 = slot4[p];

        // phase 1: all 4 plane loads issued before any use
        f32x4 xv[TC];
        #pragma unroll
        for (int ci = 0; ci < TC; ++ci)
            xv[ci] = xp[(size_t)ci * HW4 + p];

        // phase 2: LDS table gather + fma + nt store per channel
        #pragma unroll
        for (int ci = 0; ci < TC; ++ci) {
            const f32x2 t0 = tab[ci][s4.x];
            const f32x2 t1 = tab[ci][s4.y];
            const f32x2 t2 = tab[ci][s4.z];
            const f32x2 t3 = tab[ci][s4.w];
            f32x4 r;
            r.x = fmaf(t0.x, xv[ci].x, t0.y);
            r.y = fmaf(t1.x, xv[ci].y, t1.y);
            r.z = fmaf(t2.x, xv[ci].z, t2.y);
            r.w = fmaf(t3.x, xv[ci].w, t3.y);
            __builtin_nontemporal_store(r, op + (size_t)ci * HW4 + p);
        }
    }
}

extern "C" void kernel_launch(void* const* d_in, const int* in_sizes, int n_in,
                              void* d_out, int out_size, void* d_ws, size_t ws_size,
                              hipStream_t stream) {
    const float* x     = (const float*)d_in[0];
    const float* alpha = (const float*)d_in[1];
    const float* beta  = (const float*)d_in[2];
    const int*   slot  = (const int*)d_in[3];
    float* out = (float*)d_out;

    const int B = in_sizes[0] / (CHANNELS * HW);   // 16

    dim3 grid(SPLITS, CHANNELS / TC, B);           // 2 x 64 x 16 = 2048 blocks
    dim3 block(256);
    slot_affine_kernel<<<grid, block, 0, stream>>>(x, alpha, beta, slot, out);
}